// Round 5
// baseline (294.859 us; speedup 1.0000x reference)
//
#include <hip/hip_runtime.h>

typedef unsigned short u16;
typedef __attribute__((ext_vector_type(4))) float f32x4;
typedef __attribute__((ext_vector_type(8))) short bf16x8;
typedef __attribute__((ext_vector_type(4))) short bf16x4;
typedef __attribute__((ext_vector_type(4))) unsigned short u16x4;
typedef __attribute__((ext_vector_type(2))) unsigned short u16x2;

#define DEV __device__ __forceinline__

DEV float bf2f(u16 u){ unsigned x = ((unsigned)u) << 16; return __builtin_bit_cast(float, x); }
DEV u16 f2bf(float f){
  unsigned x = __builtin_bit_cast(unsigned, f);
  x += 0x7fffu + ((x >> 16) & 1u);
  return (u16)(x >> 16);
}

DEV void gload_lds16(const void* g, void* l){
  __builtin_amdgcn_global_load_lds(
      (const __attribute__((address_space(1))) unsigned int*)(unsigned long long)g,
      (__attribute__((address_space(3))) unsigned int*)(unsigned)(unsigned long long)l,
      16, 0, 0);
}

// ---------------- pack x: f32 -> bf16, row-major [4096][2048] ----------------
__global__ void __launch_bounds__(256) k_pack_x(const float* __restrict__ x,
                                                u16* __restrict__ xb, int n4){
  int i = blockIdx.x * 256 + threadIdx.x;
  if (i < n4){
    f32x4 v = *(const f32x4*)&x[i * 4];
    u16x4 o;
    o[0] = f2bf(v[0]); o[1] = f2bf(v[1]); o[2] = f2bf(v[2]); o[3] = f2bf(v[3]);
    *(u16x4*)&xb[i * 4] = o;
  }
}

// ------- pack weights: Wt[n][k] = W[k][n] (bf16) -------
__global__ void __launch_bounds__(256) k_pack_w(const float* __restrict__ Wq,
                                                const float* __restrict__ Wk,
                                                const float* __restrict__ Wv,
                                                u16* __restrict__ Wt){
  __shared__ u16 tile[64][72];
  const int n0 = blockIdx.x * 64, k0 = blockIdx.y * 64;
  const float* src; int ncols, nloc;
  if (n0 < 2048)      { src = Wq; ncols = 2048; nloc = n0; }
  else if (n0 < 2560) { src = Wk; ncols = 512;  nloc = n0 - 2048; }
  else                { src = Wv; ncols = 512;  nloc = n0 - 2560; }
  #pragma unroll
  for (int i = 0; i < 4; ++i){
    int e = i * 1024 + threadIdx.x * 4;
    int r = e >> 6, c = e & 63;
    f32x4 v = *(const f32x4*)&src[(size_t)(k0 + r) * ncols + nloc + c];
    u16x4 o;
    o[0] = f2bf(v[0]); o[1] = f2bf(v[1]); o[2] = f2bf(v[2]); o[3] = f2bf(v[3]);
    *(u16x4*)&tile[r][c] = o;
  }
  __syncthreads();
  #pragma unroll
  for (int i = 0; i < 4; ++i){
    int e = i * 1024 + threadIdx.x * 4;
    int rn = e >> 6, ck = e & 63;
    u16x4 o;
    o[0] = tile[ck + 0][rn]; o[1] = tile[ck + 1][rn];
    o[2] = tile[ck + 2][rn]; o[3] = tile[ck + 3][rn];
    *(u16x4*)&Wt[(size_t)(n0 + rn) * 2048 + k0 + ck] = o;
  }
}

// ---------------- RoPE tables: [2048][32] f32 each ----------------
__global__ void __launch_bounds__(256) k_tables(float* __restrict__ cosT,
                                                float* __restrict__ sinT){
  int i = blockIdx.x * 256 + threadIdx.x;  // 65536
  int pos = i >> 5, f = i & 31;
  float freq = expf(-(float)f * 0.28782313662425574f);  // 10000^(-f/32)
  float a = (float)pos * freq;
  cosT[i] = cosf(a);
  sinT[i] = sinf(a);
}

// ---------------- GEMM: C[4096][3072] = Xb[4096][2048] * Wt^T (bf16 MFMA) ----------------
__global__ void __launch_bounds__(256) k_gemm(const u16* __restrict__ Xb,
                                              const u16* __restrict__ Wt,
                                              u16* __restrict__ Cout){
  __shared__ u16 lA[128 * 64];
  __shared__ u16 lB[128 * 64];
  const int tid = threadIdx.x;
  const int wid = tid >> 6, lane = tid & 63;
  const int g = lane >> 4, lr = lane & 15;
  const int m0 = blockIdx.x * 128, n0 = blockIdx.y * 128;
  const int wm = wid >> 1, wn = wid & 1;

  f32x4 acc[4][4];
  #pragma unroll
  for (int i = 0; i < 4; ++i)
    #pragma unroll
    for (int j = 0; j < 4; ++j) acc[i][j] = (f32x4){0.f, 0.f, 0.f, 0.f};

  const char* gA = (const char*)Xb + (size_t)m0 * 4096;
  const char* gB = (const char*)Wt + (size_t)n0 * 4096;

  for (int kt = 0; kt < 32; ++kt){
    const int k0b = kt * 128;
    #pragma unroll
    for (int i = 0; i < 4; ++i){
      int idx = i * 256 + tid;
      int row = idx >> 3, colb = (idx & 7) << 4;
      gload_lds16(gA + (size_t)row * 4096 + k0b + colb, (char*)lA + i * 4096 + wid * 1024);
      gload_lds16(gB + (size_t)row * 4096 + k0b + colb, (char*)lB + i * 4096 + wid * 1024);
    }
    __syncthreads();
    #pragma unroll
    for (int kk = 0; kk < 2; ++kk){
      bf16x8 a[4], b[4];
      #pragma unroll
      for (int i = 0; i < 4; ++i)
        a[i] = *(const bf16x8*)&lA[(wm * 64 + i * 16 + lr) * 64 + kk * 32 + g * 8];
      #pragma unroll
      for (int j = 0; j < 4; ++j)
        b[j] = *(const bf16x8*)&lB[(wn * 64 + j * 16 + lr) * 64 + kk * 32 + g * 8];
      #pragma unroll
      for (int i = 0; i < 4; ++i)
        #pragma unroll
        for (int j = 0; j < 4; ++j)
          acc[i][j] = __builtin_amdgcn_mfma_f32_16x16x32_bf16(a[i], b[j], acc[i][j], 0, 0, 0);
    }
    __syncthreads();
  }

  #pragma unroll
  for (int i = 0; i < 4; ++i)
    #pragma unroll
    for (int j = 0; j < 4; ++j){
      int row = m0 + wm * 64 + i * 16 + g * 4;
      int col = n0 + wn * 64 + j * 16 + lr;
      #pragma unroll
      for (int r = 0; r < 4; ++r)
        Cout[(size_t)(row + r) * 3072 + col] = f2bf(acc[i][j][r]);
    }
}

// ---------------- RoPE on K: Kr[b][hk][s][d] bf16 ----------------
__global__ void __launch_bounds__(256) k_ropeK(const u16* __restrict__ C,
                                               const float* __restrict__ cosT,
                                               const float* __restrict__ sinT,
                                               u16* __restrict__ Kr){
  int idx = blockIdx.x * 256 + threadIdx.x;  // 2*8*2048*32
  int i = idx & 31;
  int s = (idx >> 5) & 2047;
  int h = (idx >> 16) & 7;
  int b = idx >> 19;
  const u16* src = &C[(size_t)(b * 2048 + s) * 3072 + 2048 + h * 64 + 2 * i];
  float xe = bf2f(src[0]), xo = bf2f(src[1]);
  float c = cosT[s * 32 + i], sn = sinT[s * 32 + i];
  u16x2 o;
  o[0] = f2bf(xe * c - xo * sn);
  o[1] = f2bf(xe * sn + xo * c);
  *(u16x2*)&Kr[((size_t)(b * 8 + h) * 2048 + s) * 64 + 2 * i] = o;
}

// ---------------- V transpose: Vt[b][hk][d][s] bf16 ----------------
__global__ void __launch_bounds__(256) k_packVt(const u16* __restrict__ C,
                                                u16* __restrict__ Vt){
  __shared__ u16 tile[64][72];
  const int s0 = blockIdx.x * 64, h = blockIdx.y, b = blockIdx.z;
  #pragma unroll
  for (int i = 0; i < 4; ++i){
    int e = i * 1024 + threadIdx.x * 4;
    int r = e >> 6, c = e & 63;
    u16x4 v = *(const u16x4*)&C[(size_t)(b * 2048 + s0 + r) * 3072 + 2560 + h * 64 + c];
    *(u16x4*)&tile[r][c] = v;
  }
  __syncthreads();
  #pragma unroll
  for (int i = 0; i < 4; ++i){
    int e = i * 1024 + threadIdx.x * 4;
    int d = e >> 6, sc = e & 63;
    u16x4 o;
    o[0] = tile[sc + 0][d]; o[1] = tile[sc + 1][d];
    o[2] = tile[sc + 2][d]; o[3] = tile[sc + 3][d];
    *(u16x4*)&Vt[((size_t)(b * 8 + h) * 64 + d) * 2048 + s0 + sc] = o;
  }
}

// ---------------- Flash attention: causal GQA, KVBLK=64, LDS double-buffered ----------------
// block = 4 waves; wave w owns q rows [qt*64+16w, +16).
// R5 = R2-passing structure + log2-domain softmax only:
//   Q pre-scaled by 0.125*log2(e); p = exp2f(s - m) via libm (OCML), unconditional
//   rescale every tile (NO defer-max), plain f2bf for P (NO cvt_pk asm), NO setprio.
__global__ void __launch_bounds__(256) k_attn(const u16* __restrict__ C,
                                              const u16* __restrict__ Kr,
                                              const u16* __restrict__ Vt,
                                              const float* __restrict__ cosT,
                                              const float* __restrict__ sinT,
                                              float* __restrict__ out){
  __shared__ u16 lK[2][4096];
  __shared__ u16 lV[2][4096];

  const int qt = 31 - (int)blockIdx.x;  // long blocks first
  const int hq = blockIdx.y, b = blockIdx.z;
  const int tid = threadIdx.x;
  const int wid = tid >> 6, lane = tid & 63;
  const int g = lane >> 4, lr = lane & 15;
  const int q16 = qt * 64 + wid * 16;
  const int hk = hq >> 2;
  const int qrow = q16 + lr;
  const float QSCL = 0.125f * 1.44269504f;  // fold /sqrt(64) and log2(e) into Q
  const float NEG = -60000.0f;              // masked-score sentinel (log2 domain)

  const char* kgbase = (const char*)(Kr + (size_t)(b * 8 + hk) * 2048 * 64);
  const char* vgbase = (const char*)(Vt + (size_t)(b * 8 + hk) * 64 * 2048);

  // Q fragments (B-operand of 16x16x32: B[k=d][col=q]), RoPE + scale in-register
  bf16x8 qf[2];
  {
    const u16* qsrc = C + (size_t)(b * 2048 + qrow) * 3072 + hq * 64;
    #pragma unroll
    for (int c = 0; c < 2; ++c){
      bf16x8 v = *(const bf16x8*)&qsrc[c * 32 + g * 8];
      int i0 = c * 16 + g * 4;
      f32x4 cs = *(const f32x4*)&cosT[qrow * 32 + i0];
      f32x4 sn = *(const f32x4*)&sinT[qrow * 32 + i0];
      bf16x8 o;
      #pragma unroll
      for (int t = 0; t < 4; ++t){
        float xe = bf2f((u16)v[2 * t]), xo = bf2f((u16)v[2 * t + 1]);
        o[2 * t]     = (short)f2bf((xe * cs[t] - xo * sn[t]) * QSCL);
        o[2 * t + 1] = (short)f2bf((xe * sn[t] + xo * cs[t]) * QSCL);
      }
      qf[c] = o;
    }
  }

  f32x4 oacc[4];
  #pragma unroll
  for (int dt = 0; dt < 4; ++dt) oacc[dt] = (f32x4){0.f, 0.f, 0.f, 0.f};
  float mold = NEG, lsum = 0.0f;

  auto STAGE = [&](int tt, int bb){
    const char* kg = kgbase + (size_t)tt * 8192;
    const char* vg = vgbase + (size_t)tt * 128;
    #pragma unroll
    for (int i = 0; i < 2; ++i){
      int dc = i * 256 + tid;
      int row = dc >> 3, cc = dc & 7;
      int sc = cc ^ (row & 7);
      gload_lds16(kg + row * 128 + sc * 16,
                  (char*)&lK[bb][0] + (i * 256 + wid * 64) * 16);
      gload_lds16(vg + (size_t)row * 4096 + sc * 16,
                  (char*)&lV[bb][0] + (i * 256 + wid * 64) * 16);
    }
  };

  int buf = 0;
  STAGE(0, 0);

  for (int t = 0; t <= qt; ++t){
    __syncthreads();                    // drains prior STAGE + all waves arrived
    if (t < qt) STAGE(t + 1, buf ^ 1);

    const char* lKb = (const char*)&lK[buf][0];
    const char* lVb = (const char*)&lV[buf][0];
    const bool diag = (t == qt);
    const int ksmax = diag ? wid : 3;
    const int sw = lr & 7;

    // ---- QK^T: S^T[kv][q] per 16-kv subtile (log2-scaled via QSCL in Q) ----
    f32x4 st[4];
    #pragma unroll
    for (int ks = 0; ks < 4; ++ks){
      st[ks] = (f32x4){0.f, 0.f, 0.f, 0.f};
      if (ks <= ksmax){
        int row = ks * 16 + lr;
        bf16x8 k0 = *(const bf16x8*)(lKb + row * 128 + ((0 + g) ^ sw) * 16);
        bf16x8 k1 = *(const bf16x8*)(lKb + row * 128 + ((4 + g) ^ sw) * 16);
        st[ks] = __builtin_amdgcn_mfma_f32_16x16x32_bf16(k0, qf[0], st[ks], 0, 0, 0);
        st[ks] = __builtin_amdgcn_mfma_f32_16x16x32_bf16(k1, qf[1], st[ks], 0, 0, 0);
      }
    }

    // ---- online softmax (log2 domain), p fully initialized, unconditional rescale ----
    float p[4][4];
    float mt = NEG;
    #pragma unroll
    for (int ks = 0; ks < 4; ++ks){
      #pragma unroll
      for (int r = 0; r < 4; ++r){
        float v = NEG;
        if (ks <= ksmax){
          v = st[ks][r];
          if (diag && ks == wid && (4 * g + r > lr)) v = NEG;
        }
        p[ks][r] = v;
        mt = fmaxf(mt, v);
      }
    }
    mt = fmaxf(mt, __shfl_xor(mt, 16));
    mt = fmaxf(mt, __shfl_xor(mt, 32));
    float mnew = fmaxf(mold, mt);
    float al = exp2f(mold - mnew);
    float ls = 0.f;
    #pragma unroll
    for (int ks = 0; ks < 4; ++ks){
      if (ks <= ksmax){
        #pragma unroll
        for (int r = 0; r < 4; ++r){
          float e = exp2f(p[ks][r] - mnew);
          p[ks][r] = e; ls += e;
        }
      }
    }
    ls += __shfl_xor(ls, 16);
    ls += __shfl_xor(ls, 32);
    lsum = lsum * al + ls;
    mold = mnew;

    // rescale O (rows are q_local = 4g+r)
    #pragma unroll
    for (int r = 0; r < 4; ++r){
      float ar = __shfl(al, 4 * g + r);
      oacc[0][r] *= ar; oacc[1][r] *= ar; oacc[2][r] *= ar; oacc[3][r] *= ar;
    }

    // ---- PV: A[row=q=lr][k=kv=4g+j] = p, B from V^T LDS tile ----
    #pragma unroll
    for (int ks = 0; ks < 4; ++ks){
      if (ks <= ksmax){
        bf16x4 pa;
        #pragma unroll
        for (int j = 0; j < 4; ++j) pa[j] = (short)f2bf(p[ks][j]);
        int chunk = ks * 2 + (g >> 1);
        #pragma unroll
        for (int dt = 0; dt < 4; ++dt){
          int row = dt * 16 + lr;
          bf16x4 vb = *(const bf16x4*)(lVb + row * 128 + (chunk ^ sw) * 16 + (g & 1) * 8);
          oacc[dt] = __builtin_amdgcn_mfma_f32_16x16x16bf16_1k(pa, vb, oacc[dt], 0, 0, 0);
        }
      }
    }

    buf ^= 1;
  }

  float inv[4];
  #pragma unroll
  for (int r = 0; r < 4; ++r) inv[r] = 1.0f / __shfl(lsum, 4 * g + r);
  float* obase = out + (size_t)(b * 2048 + q16) * 2048 + hq * 64;
  #pragma unroll
  for (int dt = 0; dt < 4; ++dt)
    #pragma unroll
    for (int r = 0; r < 4; ++r)
      obase[(size_t)(4 * g + r) * 2048 + dt * 16 + lr] = oacc[dt][r] * inv[r];
}

// ---------------- launch ----------------
extern "C" void kernel_launch(void* const* d_in, const int* in_sizes, int n_in,
                              void* d_out, int out_size, void* d_ws, size_t ws_size,
                              hipStream_t stream) {
  const float* x  = (const float*)d_in[0];
  const float* Wq = (const float*)d_in[1];
  const float* Wk = (const float*)d_in[2];
  const float* Wv = (const float*)d_in[3];
  float* out = (float*)d_out;
  char* ws = (char*)d_ws;

  u16* Xb   = (u16*)(ws + 0);            // 16,777,216
  u16* Wt   = (u16*)(ws + 16777216);     // 12,582,912
  u16* Cb   = (u16*)(ws + 29360128);     // 25,165,824
  u16* Kr   = (u16*)(ws + 54525952);     //  4,194,304
  u16* Vt   = (u16*)(ws + 58720256);     //  4,194,304
  float* cosT = (float*)(ws + 62914560); //    262,144
  float* sinT = (float*)(ws + 63176704); //    262,144

  k_pack_x<<<8192, 256, 0, stream>>>(x, Xb, 2097152);
  k_pack_w<<<dim3(48, 32), 256, 0, stream>>>(Wq, Wk, Wv, Wt);
  k_tables<<<256, 256, 0, stream>>>(cosT, sinT);
  k_gemm<<<dim3(32, 24), 256, 0, stream>>>(Xb, Wt, Cb);
  k_ropeK<<<4096, 256, 0, stream>>>(Cb, cosT, sinT, Kr);
  k_packVt<<<dim3(32, 8, 2), 256, 0, stream>>>(Cb, Vt);
  k_attn<<<dim3(32, 32, 2), 256, 0, stream>>>(Cb, Kr, Vt, cosT, sinT, out);
}

// Round 7
// 249.201 us; speedup vs baseline: 1.1832x; 1.1832x over previous
//
#include <hip/hip_runtime.h>

typedef unsigned short u16;
typedef __attribute__((ext_vector_type(4))) float f32x4;
typedef __attribute__((ext_vector_type(8))) short bf16x8;
typedef __attribute__((ext_vector_type(4))) short bf16x4;
typedef __attribute__((ext_vector_type(4))) unsigned short u16x4;
typedef __attribute__((ext_vector_type(2))) unsigned short u16x2;

#define DEV __device__ __forceinline__

DEV float bf2f(u16 u){ unsigned x = ((unsigned)u) << 16; return __builtin_bit_cast(float, x); }
DEV u16 f2bf(float f){
  unsigned x = __builtin_bit_cast(unsigned, f);
  x += 0x7fffu + ((x >> 16) & 1u);
  return (u16)(x >> 16);
}
// pack {lo,hi} f32 -> two bf16 (truncation) in one v_perm_b32
DEV unsigned pack_bf16_trunc(float lo, float hi){
  return __builtin_amdgcn_perm(__builtin_bit_cast(unsigned, hi),
                               __builtin_bit_cast(unsigned, lo), 0x07060302u);
}

DEV void gload_lds16(const void* g, void* l){
  __builtin_amdgcn_global_load_lds(
      (const __attribute__((address_space(1))) unsigned int*)(unsigned long long)g,
      (__attribute__((address_space(3))) unsigned int*)(unsigned)(unsigned long long)l,
      16, 0, 0);
}

// ---------------- pack x: f32 -> bf16, row-major [4096][2048] ----------------
__global__ void __launch_bounds__(256) k_pack_x(const float* __restrict__ x,
                                                u16* __restrict__ xb, int n4){
  int i = blockIdx.x * 256 + threadIdx.x;
  if (i < n4){
    f32x4 v = *(const f32x4*)&x[i * 4];
    u16x4 o;
    o[0] = f2bf(v[0]); o[1] = f2bf(v[1]); o[2] = f2bf(v[2]); o[3] = f2bf(v[3]);
    *(u16x4*)&xb[i * 4] = o;
  }
}

// ------- pack weights: Wt[n][k] = W[k][n] (bf16) -------
__global__ void __launch_bounds__(256) k_pack_w(const float* __restrict__ Wq,
                                                const float* __restrict__ Wk,
                                                const float* __restrict__ Wv,
                                                u16* __restrict__ Wt){
  __shared__ u16 tile[64][72];
  const int n0 = blockIdx.x * 64, k0 = blockIdx.y * 64;
  const float* src; int ncols, nloc;
  if (n0 < 2048)      { src = Wq; ncols = 2048; nloc = n0; }
  else if (n0 < 2560) { src = Wk; ncols = 512;  nloc = n0 - 2048; }
  else                { src = Wv; ncols = 512;  nloc = n0 - 2560; }
  #pragma unroll
  for (int i = 0; i < 4; ++i){
    int e = i * 1024 + threadIdx.x * 4;
    int r = e >> 6, c = e & 63;
    f32x4 v = *(const f32x4*)&src[(size_t)(k0 + r) * ncols + nloc + c];
    u16x4 o;
    o[0] = f2bf(v[0]); o[1] = f2bf(v[1]); o[2] = f2bf(v[2]); o[3] = f2bf(v[3]);
    *(u16x4*)&tile[r][c] = o;
  }
  __syncthreads();
  #pragma unroll
  for (int i = 0; i < 4; ++i){
    int e = i * 1024 + threadIdx.x * 4;
    int rn = e >> 6, ck = e & 63;
    u16x4 o;
    o[0] = tile[ck + 0][rn]; o[1] = tile[ck + 1][rn];
    o[2] = tile[ck + 2][rn]; o[3] = tile[ck + 3][rn];
    *(u16x4*)&Wt[(size_t)(n0 + rn) * 2048 + k0 + ck] = o;
  }
}

// ---------------- RoPE tables: [2048][32] f32 each ----------------
__global__ void __launch_bounds__(256) k_tables(float* __restrict__ cosT,
                                                float* __restrict__ sinT){
  int i = blockIdx.x * 256 + threadIdx.x;  // 65536
  int pos = i >> 5, f = i & 31;
  float freq = expf(-(float)f * 0.28782313662425574f);  // 10000^(-f/32)
  float a = (float)pos * freq;
  cosT[i] = cosf(a);
  sinT[i] = sinf(a);
}

// ---------------- GEMM: C[4096][3072] = Xb[4096][2048] * Wt^T (bf16 MFMA) ----------------
__global__ void __launch_bounds__(256) k_gemm(const u16* __restrict__ Xb,
                                              const u16* __restrict__ Wt,
                                              u16* __restrict__ Cout){
  __shared__ u16 lA[128 * 64];
  __shared__ u16 lB[128 * 64];
  const int tid = threadIdx.x;
  const int wid = tid >> 6, lane = tid & 63;
  const int g = lane >> 4, lr = lane & 15;
  const int m0 = blockIdx.x * 128, n0 = blockIdx.y * 128;
  const int wm = wid >> 1, wn = wid & 1;

  f32x4 acc[4][4];
  #pragma unroll
  for (int i = 0; i < 4; ++i)
    #pragma unroll
    for (int j = 0; j < 4; ++j) acc[i][j] = (f32x4){0.f, 0.f, 0.f, 0.f};

  const char* gA = (const char*)Xb + (size_t)m0 * 4096;
  const char* gB = (const char*)Wt + (size_t)n0 * 4096;

  for (int kt = 0; kt < 32; ++kt){
    const int k0b = kt * 128;
    #pragma unroll
    for (int i = 0; i < 4; ++i){
      int idx = i * 256 + tid;
      int row = idx >> 3, colb = (idx & 7) << 4;
      gload_lds16(gA + (size_t)row * 4096 + k0b + colb, (char*)lA + i * 4096 + wid * 1024);
      gload_lds16(gB + (size_t)row * 4096 + k0b + colb, (char*)lB + i * 4096 + wid * 1024);
    }
    __syncthreads();
    #pragma unroll
    for (int kk = 0; kk < 2; ++kk){
      bf16x8 a[4], b[4];
      #pragma unroll
      for (int i = 0; i < 4; ++i)
        a[i] = *(const bf16x8*)&lA[(wm * 64 + i * 16 + lr) * 64 + kk * 32 + g * 8];
      #pragma unroll
      for (int j = 0; j < 4; ++j)
        b[j] = *(const bf16x8*)&lB[(wn * 64 + j * 16 + lr) * 64 + kk * 32 + g * 8];
      #pragma unroll
      for (int i = 0; i < 4; ++i)
        #pragma unroll
        for (int j = 0; j < 4; ++j)
          acc[i][j] = __builtin_amdgcn_mfma_f32_16x16x32_bf16(a[i], b[j], acc[i][j], 0, 0, 0);
    }
    __syncthreads();
  }

  #pragma unroll
  for (int i = 0; i < 4; ++i)
    #pragma unroll
    for (int j = 0; j < 4; ++j){
      int row = m0 + wm * 64 + i * 16 + g * 4;
      int col = n0 + wn * 64 + j * 16 + lr;
      #pragma unroll
      for (int r = 0; r < 4; ++r)
        Cout[(size_t)(row + r) * 3072 + col] = f2bf(acc[i][j][r]);
    }
}

// ---------------- RoPE on K: Kr[b][hk][s][d] bf16 ----------------
__global__ void __launch_bounds__(256) k_ropeK(const u16* __restrict__ C,
                                               const float* __restrict__ cosT,
                                               const float* __restrict__ sinT,
                                               u16* __restrict__ Kr){
  int idx = blockIdx.x * 256 + threadIdx.x;  // 2*8*2048*32
  int i = idx & 31;
  int s = (idx >> 5) & 2047;
  int h = (idx >> 16) & 7;
  int b = idx >> 19;
  const u16* src = &C[(size_t)(b * 2048 + s) * 3072 + 2048 + h * 64 + 2 * i];
  float xe = bf2f(src[0]), xo = bf2f(src[1]);
  float c = cosT[s * 32 + i], sn = sinT[s * 32 + i];
  u16x2 o;
  o[0] = f2bf(xe * c - xo * sn);
  o[1] = f2bf(xe * sn + xo * c);
  *(u16x2*)&Kr[((size_t)(b * 8 + h) * 2048 + s) * 64 + 2 * i] = o;
}

// ---------------- V transpose: Vt[b][hk][d][s] bf16 ----------------
__global__ void __launch_bounds__(256) k_packVt(const u16* __restrict__ C,
                                                u16* __restrict__ Vt){
  __shared__ u16 tile[64][72];
  const int s0 = blockIdx.x * 64, h = blockIdx.y, b = blockIdx.z;
  #pragma unroll
  for (int i = 0; i < 4; ++i){
    int e = i * 1024 + threadIdx.x * 4;
    int r = e >> 6, c = e & 63;
    u16x4 v = *(const u16x4*)&C[(size_t)(b * 2048 + s0 + r) * 3072 + 2560 + h * 64 + c];
    *(u16x4*)&tile[r][c] = v;
  }
  __syncthreads();
  #pragma unroll
  for (int i = 0; i < 4; ++i){
    int e = i * 1024 + threadIdx.x * 4;
    int d = e >> 6, sc = e & 63;
    u16x4 o;
    o[0] = tile[sc + 0][d]; o[1] = tile[sc + 1][d];
    o[2] = tile[sc + 2][d]; o[3] = tile[sc + 3][d];
    *(u16x4*)&Vt[((size_t)(b * 8 + h) * 64 + d) * 2048 + s0 + sc] = o;
  }
}

// ---------------- Flash attention: causal GQA, KVBLK=64, LDS double-buffered ----------------
// block = 4 waves; wave w owns q rows [qt*64+16w, +16).
// R7 = R5(green) + diag-peel + __expf (R2-proven) + v_perm P-pack + exact skip-rescale.
// Quarantined (NaN on this toolchain, R3/R4/R6): __builtin_amdgcn_exp2f, cvt_pk asm, setprio.
__global__ void __launch_bounds__(256) k_attn(const u16* __restrict__ C,
                                              const u16* __restrict__ Kr,
                                              const u16* __restrict__ Vt,
                                              const float* __restrict__ cosT,
                                              const float* __restrict__ sinT,
                                              float* __restrict__ out){
  __shared__ u16 lK[2][4096];
  __shared__ u16 lV[2][4096];

  const int qt = 31 - (int)blockIdx.x;  // long blocks first
  const int hq = blockIdx.y, b = blockIdx.z;
  const int tid = threadIdx.x;
  const int wid = tid >> 6, lane = tid & 63;
  const int g = lane >> 4, lr = lane & 15;
  const int q16 = qt * 64 + wid * 16;
  const int hk = hq >> 2;
  const int qrow = q16 + lr;
  const float QSCL = 0.125f;            // fold 1/sqrt(64) into Q (natural-exp domain)
  const float NEG = -60000.0f;          // masked-score sentinel
  const int sw = lr & 7;

  const char* kgbase = (const char*)(Kr + (size_t)(b * 8 + hk) * 2048 * 64);
  const char* vgbase = (const char*)(Vt + (size_t)(b * 8 + hk) * 64 * 2048);

  // Q fragments (B-operand of 16x16x32: B[k=d][col=q]), RoPE + scale in-register
  bf16x8 qf[2];
  {
    const u16* qsrc = C + (size_t)(b * 2048 + qrow) * 3072 + hq * 64;
    #pragma unroll
    for (int c = 0; c < 2; ++c){
      bf16x8 v = *(const bf16x8*)&qsrc[c * 32 + g * 8];
      int i0 = c * 16 + g * 4;
      f32x4 cs = *(const f32x4*)&cosT[qrow * 32 + i0];
      f32x4 sn = *(const f32x4*)&sinT[qrow * 32 + i0];
      bf16x8 o;
      #pragma unroll
      for (int t = 0; t < 4; ++t){
        float xe = bf2f((u16)v[2 * t]), xo = bf2f((u16)v[2 * t + 1]);
        o[2 * t]     = (short)f2bf((xe * cs[t] - xo * sn[t]) * QSCL);
        o[2 * t + 1] = (short)f2bf((xe * sn[t] + xo * cs[t]) * QSCL);
      }
      qf[c] = o;
    }
  }

  f32x4 oacc[4];
  #pragma unroll
  for (int dt = 0; dt < 4; ++dt) oacc[dt] = (f32x4){0.f, 0.f, 0.f, 0.f};
  float mold = NEG, lsum = 0.0f;

  auto STAGE = [&](int tt, int bb){
    const char* kg = kgbase + (size_t)tt * 8192;
    const char* vg = vgbase + (size_t)tt * 128;
    #pragma unroll
    for (int i = 0; i < 2; ++i){
      int dc = i * 256 + tid;
      int row = dc >> 3, cc = dc & 7;
      int sc = cc ^ (row & 7);
      gload_lds16(kg + row * 128 + sc * 16,
                  (char*)&lK[bb][0] + (i * 256 + wid * 64) * 16);
      gload_lds16(vg + (size_t)row * 4096 + sc * 16,
                  (char*)&lV[bb][0] + (i * 256 + wid * 64) * 16);
    }
  };

  int buf = 0;
  STAGE(0, 0);

  // ================= hot loop: fully-unmasked tiles t = 0..qt-1 =================
  for (int t = 0; t < qt; ++t){
    __syncthreads();
    STAGE(t + 1, buf ^ 1);

    const char* lKb = (const char*)&lK[buf][0];
    const char* lVb = (const char*)&lV[buf][0];

    // ---- QK^T: S^T[kv][q], all 4 subtiles unmasked ----
    f32x4 st[4];
    #pragma unroll
    for (int ks = 0; ks < 4; ++ks){
      st[ks] = (f32x4){0.f, 0.f, 0.f, 0.f};
      int row = ks * 16 + lr;
      bf16x8 k0 = *(const bf16x8*)(lKb + row * 128 + ((0 + g) ^ sw) * 16);
      bf16x8 k1 = *(const bf16x8*)(lKb + row * 128 + ((4 + g) ^ sw) * 16);
      st[ks] = __builtin_amdgcn_mfma_f32_16x16x32_bf16(k0, qf[0], st[ks], 0, 0, 0);
      st[ks] = __builtin_amdgcn_mfma_f32_16x16x32_bf16(k1, qf[1], st[ks], 0, 0, 0);
    }

    // ---- online softmax, no masks ----
    float mt = fmaxf(fmaxf(fmaxf(st[0][0], st[0][1]), fmaxf(st[0][2], st[0][3])),
                     fmaxf(fmaxf(st[1][0], st[1][1]), fmaxf(st[1][2], st[1][3])));
    mt = fmaxf(mt, fmaxf(fmaxf(fmaxf(st[2][0], st[2][1]), fmaxf(st[2][2], st[2][3])),
                         fmaxf(fmaxf(st[3][0], st[3][1]), fmaxf(st[3][2], st[3][3]))));
    mt = fmaxf(mt, __shfl_xor(mt, 16));
    mt = fmaxf(mt, __shfl_xor(mt, 32));
    if (__any(mt > mold)){              // exact skip: if false, al==1 identically
      float mnew = fmaxf(mold, mt);
      float al = __expf(mold - mnew);
      lsum *= al;
      #pragma unroll
      for (int r = 0; r < 4; ++r){
        float ar = __shfl(al, 4 * g + r);
        oacc[0][r] *= ar; oacc[1][r] *= ar; oacc[2][r] *= ar; oacc[3][r] *= ar;
      }
      mold = mnew;
    }
    float p[4][4];
    float ls = 0.f;
    #pragma unroll
    for (int ks = 0; ks < 4; ++ks){
      #pragma unroll
      for (int r = 0; r < 4; ++r){
        float e = __expf(st[ks][r] - mold);
        p[ks][r] = e; ls += e;
      }
    }
    ls += __shfl_xor(ls, 16);
    ls += __shfl_xor(ls, 32);
    lsum += ls;

    // ---- PV: A[row=q=lr][k=kv=4g+j] = p, B from V^T LDS tile ----
    #pragma unroll
    for (int ks = 0; ks < 4; ++ks){
      union { unsigned u[2]; bf16x4 v; } pu;
      pu.u[0] = pack_bf16_trunc(p[ks][0], p[ks][1]);
      pu.u[1] = pack_bf16_trunc(p[ks][2], p[ks][3]);
      bf16x4 pa = pu.v;
      int chunk = ks * 2 + (g >> 1);
      #pragma unroll
      for (int dt = 0; dt < 4; ++dt){
        int row = dt * 16 + lr;
        bf16x4 vb = *(const bf16x4*)(lVb + row * 128 + (chunk ^ sw) * 16 + (g & 1) * 8);
        oacc[dt] = __builtin_amdgcn_mfma_f32_16x16x16bf16_1k(pa, vb, oacc[dt], 0, 0, 0);
      }
    }

    buf ^= 1;
  }

  // ================= diag tile t = qt (masked epilogue) =================
  {
    __syncthreads();
    const char* lKb = (const char*)&lK[buf][0];
    const char* lVb = (const char*)&lV[buf][0];
    const int ksmax = wid;

    f32x4 st[4];
    #pragma unroll
    for (int ks = 0; ks < 4; ++ks){
      st[ks] = (f32x4){0.f, 0.f, 0.f, 0.f};
      if (ks <= ksmax){
        int row = ks * 16 + lr;
        bf16x8 k0 = *(const bf16x8*)(lKb + row * 128 + ((0 + g) ^ sw) * 16);
        bf16x8 k1 = *(const bf16x8*)(lKb + row * 128 + ((4 + g) ^ sw) * 16);
        st[ks] = __builtin_amdgcn_mfma_f32_16x16x32_bf16(k0, qf[0], st[ks], 0, 0, 0);
        st[ks] = __builtin_amdgcn_mfma_f32_16x16x32_bf16(k1, qf[1], st[ks], 0, 0, 0);
      }
    }

    float p[4][4];
    float mt = NEG;
    #pragma unroll
    for (int ks = 0; ks < 4; ++ks){
      #pragma unroll
      for (int r = 0; r < 4; ++r){
        float v = NEG;
        if (ks <= ksmax){
          v = st[ks][r];
          if (ks == ksmax && (4 * g + r > lr)) v = NEG;
        }
        p[ks][r] = v;
        mt = fmaxf(mt, v);
      }
    }
    mt = fmaxf(mt, __shfl_xor(mt, 16));
    mt = fmaxf(mt, __shfl_xor(mt, 32));
    float mnew = fmaxf(mold, mt);
    float al = __expf(mold - mnew);
    lsum *= al;
    #pragma unroll
    for (int r = 0; r < 4; ++r){
      float ar = __shfl(al, 4 * g + r);
      oacc[0][r] *= ar; oacc[1][r] *= ar; oacc[2][r] *= ar; oacc[3][r] *= ar;
    }
    float ls = 0.f;
    #pragma unroll
    for (int ks = 0; ks < 4; ++ks){
      if (ks <= ksmax){
        #pragma unroll
        for (int r = 0; r < 4; ++r){
          float e = __expf(p[ks][r] - mnew);
          p[ks][r] = e; ls += e;
        }
      }
    }
    ls += __shfl_xor(ls, 16);
    ls += __shfl_xor(ls, 32);
    lsum += ls;

    #pragma unroll
    for (int ks = 0; ks < 4; ++ks){
      if (ks <= ksmax){
        union { unsigned u[2]; bf16x4 v; } pu;
        pu.u[0] = pack_bf16_trunc(p[ks][0], p[ks][1]);
        pu.u[1] = pack_bf16_trunc(p[ks][2], p[ks][3]);
        bf16x4 pa = pu.v;
        int chunk = ks * 2 + (g >> 1);
        #pragma unroll
        for (int dt = 0; dt < 4; ++dt){
          int row = dt * 16 + lr;
          bf16x4 vb = *(const bf16x4*)(lVb + row * 128 + (chunk ^ sw) * 16 + (g & 1) * 8);
          oacc[dt] = __builtin_amdgcn_mfma_f32_16x16x16bf16_1k(pa, vb, oacc[dt], 0, 0, 0);
        }
      }
    }
  }

  float inv[4];
  #pragma unroll
  for (int r = 0; r < 4; ++r) inv[r] = 1.0f / __shfl(lsum, 4 * g + r);
  float* obase = out + (size_t)(b * 2048 + q16) * 2048 + hq * 64;
  #pragma unroll
  for (int dt = 0; dt < 4; ++dt)
    #pragma unroll
    for (int r = 0; r < 4; ++r)
      obase[(size_t)(4 * g + r) * 2048 + dt * 16 + lr] = oacc[dt][r] * inv[r];
}

// ---------------- launch ----------------
extern "C" void kernel_launch(void* const* d_in, const int* in_sizes, int n_in,
                              void* d_out, int out_size, void* d_ws, size_t ws_size,
                              hipStream_t stream) {
  const float* x  = (const float*)d_in[0];
  const float* Wq = (const float*)d_in[1];
  const float* Wk = (const float*)d_in[2];
  const float* Wv = (const float*)d_in[3];
  float* out = (float*)d_out;
  char* ws = (char*)d_ws;

  u16* Xb   = (u16*)(ws + 0);            // 16,777,216
  u16* Wt   = (u16*)(ws + 16777216);     // 12,582,912
  u16* Cb   = (u16*)(ws + 29360128);     // 25,165,824
  u16* Kr   = (u16*)(ws + 54525952);     //  4,194,304
  u16* Vt   = (u16*)(ws + 58720256);     //  4,194,304
  float* cosT = (float*)(ws + 62914560); //    262,144
  float* sinT = (float*)(ws + 63176704); //    262,144

  k_pack_x<<<8192, 256, 0, stream>>>(x, Xb, 2097152);
  k_pack_w<<<dim3(48, 32), 256, 0, stream>>>(Wq, Wk, Wv, Wt);
  k_tables<<<256, 256, 0, stream>>>(cosT, sinT);
  k_gemm<<<dim3(32, 24), 256, 0, stream>>>(Xb, Wt, Cb);
  k_ropeK<<<4096, 256, 0, stream>>>(Cb, cosT, sinT, Kr);
  k_packVt<<<dim3(32, 8, 2), 256, 0, stream>>>(Cb, Vt);
  k_attn<<<dim3(32, 32, 2), 256, 0, stream>>>(Cb, Kr, Vt, cosT, sinT, out);
}